// Round 3
// baseline (1424.023 us; speedup 1.0000x reference)
//
#include <hip/hip_runtime.h>

// h <- A_norm h, 12 times, in "u-space": u = invs .* h, so each layer is
//   u'[d] = (1/deg[d]) * (u[d] + sum_{s in N(d)} u[s])
// and the final output is h12 = sqrt(deg) .* u12.
// CSR (dst-bucketed) built per call; rows padded to multiples of 4 with
// self-pointing entries, compensated exactly by corr = 1 - pads.

#define NB 256

__global__ void k_init(int* __restrict__ cnt, unsigned* __restrict__ mask, int n, int nm) {
    int i = blockIdx.x * NB + threadIdx.x;
    if (i < n) cnt[i] = 0;
    if (i < nm) mask[i] = 0u;
}

__global__ void k_count(const int* __restrict__ src, const int* __restrict__ dst,
                        int* __restrict__ cnt, unsigned* __restrict__ mask, int e) {
    int i = blockIdx.x * NB + threadIdx.x;
    if (i < e) {
        int s = src[i], d = dst[i];
        atomicOr(&mask[s >> 5], 1u << (s & 31));
        atomicOr(&mask[d >> 5], 1u << (d & 31));
        atomicAdd(&cnt[d], 1);
    }
}

// u0 = (nonisolated ? x * rsqrt(deg) : 0), written as one float4 per thread
__global__ void k_init_u(const float4* __restrict__ x, const int* __restrict__ cnt,
                         const unsigned* __restrict__ mask, float4* __restrict__ u, int n4) {
    int i = blockIdx.x * NB + threadIdx.x;
    if (i >= n4) return;
    int node = i >> 2;
    bool ni = (mask[node >> 5] >> (node & 31)) & 1u;
    float is = rsqrtf((float)(cnt[node] + 1));
    float4 v = x[i];
    float c = ni ? is : 0.0f;
    v.x *= c; v.y *= c; v.z *= c; v.w *= c;
    u[i] = v;
}

// ---- exclusive scan of padded counts ((cnt+3)&~3) -> rowptr, cursor ----
__global__ void k_scan1(const int* __restrict__ cnt, int* __restrict__ partial, int n) {
    __shared__ int sd[NB];
    int i = blockIdx.x * NB + threadIdx.x;
    sd[threadIdx.x] = (i < n) ? ((cnt[i] + 3) & ~3) : 0;
    __syncthreads();
    for (int s = NB / 2; s > 0; s >>= 1) {
        if (threadIdx.x < s) sd[threadIdx.x] += sd[threadIdx.x + s];
        __syncthreads();
    }
    if (threadIdx.x == 0) partial[blockIdx.x] = sd[0];
}

__global__ void k_scan2(int* __restrict__ partial, int nb) {
    __shared__ int sd[512];
    int t = threadIdx.x;
    int v = (t < nb) ? partial[t] : 0;
    sd[t] = v;
    __syncthreads();
    for (int off = 1; off < 512; off <<= 1) {
        int add = (t >= off) ? sd[t - off] : 0;
        __syncthreads();
        sd[t] += add;
        __syncthreads();
    }
    if (t < nb) partial[t] = sd[t] - v;   // exclusive
}

__global__ void k_scan3(const int* __restrict__ cnt, const int* __restrict__ partial,
                        int* __restrict__ rowptr, int* __restrict__ cursor, int n) {
    __shared__ int sd[NB];
    int i = blockIdx.x * NB + threadIdx.x;
    int v = (i < n) ? ((cnt[i] + 3) & ~3) : 0;
    sd[threadIdx.x] = v;
    __syncthreads();
    for (int off = 1; off < NB; off <<= 1) {
        int add = (threadIdx.x >= off) ? sd[threadIdx.x - off] : 0;
        __syncthreads();
        sd[threadIdx.x] += add;
        __syncthreads();
    }
    int ex = sd[threadIdx.x] - v + partial[blockIdx.x];
    if (i < n) { rowptr[i] = ex; cursor[i] = ex; }
    if (i == n - 1) rowptr[n] = ex + v;
}

// fill pad slots (rowptr[i]+cnt[i] .. rowptr[i+1]) with the node's own index
__global__ void k_padfill(const int* __restrict__ rowptr, const int* __restrict__ cnt,
                          int* __restrict__ adj, int n) {
    int i = blockIdx.x * NB + threadIdx.x;
    if (i >= n) return;
    int b = rowptr[i] + cnt[i], en = rowptr[i + 1];
    for (int p = b; p < en; ++p) adj[p] = i;
}

__global__ void k_scatter(const int* __restrict__ src, const int* __restrict__ dst,
                          int* __restrict__ cursor, int* __restrict__ adj, int e) {
    int i = blockIdx.x * NB + threadIdx.x;
    if (i < e) {
        int d = dst[i];
        int pos = atomicAdd(&cursor[d], 1);
        atomicExch(&adj[pos], src[i]);   // atomic path: no dirty-line HBM write-through
    }
}

// 4 threads per node; lane q owns float4 quadrant q. 8 gathers in flight.
__global__ void k_layer(const int* __restrict__ rowptr, const int* __restrict__ cnt,
                        const int* __restrict__ adj,
                        const float4* __restrict__ u, float4* __restrict__ un, int n) {
    int t = blockIdx.x * NB + threadIdx.x;
    int node = t >> 2, q = t & 3;
    if (node >= n) return;
    int beg = rowptr[node], endp = rowptr[node + 1];
    int deg = cnt[node];
    float corr = (float)(1 - (endp - beg - deg));   // 1 - pads
    float c0 = 1.0f / (float)(deg + 1);
    float4 self = u[(size_t)node * 4 + q];
    float ax = 0.f, ay = 0.f, az = 0.f, aw = 0.f;
    float bx = 0.f, by = 0.f, bz = 0.f, bw = 0.f;
    int p = beg;
    for (; p + 8 <= endp; p += 8) {
        int4 sa = *(const int4*)(adj + p);
        int4 sb = *(const int4*)(adj + p + 4);
        float4 v0 = u[(size_t)sa.x * 4 + q];
        float4 v1 = u[(size_t)sa.y * 4 + q];
        float4 v2 = u[(size_t)sa.z * 4 + q];
        float4 v3 = u[(size_t)sa.w * 4 + q];
        float4 w0 = u[(size_t)sb.x * 4 + q];
        float4 w1 = u[(size_t)sb.y * 4 + q];
        float4 w2 = u[(size_t)sb.z * 4 + q];
        float4 w3 = u[(size_t)sb.w * 4 + q];
        ax += (v0.x + v1.x) + (v2.x + v3.x);
        ay += (v0.y + v1.y) + (v2.y + v3.y);
        az += (v0.z + v1.z) + (v2.z + v3.z);
        aw += (v0.w + v1.w) + (v2.w + v3.w);
        bx += (w0.x + w1.x) + (w2.x + w3.x);
        by += (w0.y + w1.y) + (w2.y + w3.y);
        bz += (w0.z + w1.z) + (w2.z + w3.z);
        bw += (w0.w + w1.w) + (w2.w + w3.w);
    }
    if (p < endp) {
        int4 sa = *(const int4*)(adj + p);
        float4 v0 = u[(size_t)sa.x * 4 + q];
        float4 v1 = u[(size_t)sa.y * 4 + q];
        float4 v2 = u[(size_t)sa.z * 4 + q];
        float4 v3 = u[(size_t)sa.w * 4 + q];
        ax += (v0.x + v1.x) + (v2.x + v3.x);
        ay += (v0.y + v1.y) + (v2.y + v3.y);
        az += (v0.z + v1.z) + (v2.z + v3.z);
        aw += (v0.w + v1.w) + (v2.w + v3.w);
    }
    float4 r;
    r.x = (ax + bx + corr * self.x) * c0;
    r.y = (ay + by + corr * self.y) * c0;
    r.z = (az + bz + corr * self.z) * c0;
    r.w = (aw + bw + corr * self.w) * c0;
    un[(size_t)node * 4 + q] = r;
}

// h12 = sqrt(deg) .* u12, in place on d_out
__global__ void k_finish(float4* __restrict__ h, const int* __restrict__ cnt, int n4) {
    int i = blockIdx.x * NB + threadIdx.x;
    if (i >= n4) return;
    int node = i >> 2;
    float s = sqrtf((float)(cnt[node] + 1));
    float4 v = h[i];
    v.x *= s; v.y *= s; v.z *= s; v.w *= s;
    h[i] = v;
}

extern "C" void kernel_launch(void* const* d_in, const int* in_sizes, int n_in,
                              void* d_out, int out_size, void* d_ws, size_t ws_size,
                              hipStream_t stream) {
    const float* x  = (const float*)d_in[0];
    const int*   ei = (const int*)d_in[1];
    const int n = in_sizes[0] / 16;   // 100000
    const int e = in_sizes[1] / 2;    // 3200000
    const int* src = ei;
    const int* dst = ei + e;
    const int nm = (n + 31) / 32;

    char* ws = (char*)d_ws;
    auto take = [&](size_t bytes) {
        char* p = ws;
        ws += (bytes + 255) & ~(size_t)255;
        return p;
    };
    int*      cnt     = (int*)take((size_t)n * sizeof(int));
    unsigned* mask    = (unsigned*)take((size_t)nm * sizeof(unsigned));
    int*      rowptr  = (int*)take((size_t)(n + 1) * sizeof(int));
    int*      cursor  = (int*)take((size_t)n * sizeof(int));
    int*      partial = (int*)take(512 * sizeof(int));
    int*      adj     = (int*)take((size_t)(e + 3 * n + 8) * sizeof(int));
    float*    uws     = (float*)take((size_t)n * 16 * sizeof(float));
    float*    uout    = (float*)d_out;

    const int gn  = (n + NB - 1) / NB;       // 391
    const int ge  = (e + NB - 1) / NB;
    const int gn4 = (n * 4 + NB - 1) / NB;   // 1563

    k_init<<<gn, NB, 0, stream>>>(cnt, mask, n, nm);
    k_count<<<ge, NB, 0, stream>>>(src, dst, cnt, mask, e);
    k_init_u<<<gn4, NB, 0, stream>>>((const float4*)x, cnt, mask, (float4*)uout, n * 4);
    k_scan1<<<gn, NB, 0, stream>>>(cnt, partial, n);
    k_scan2<<<1, 512, 0, stream>>>(partial, gn);
    k_scan3<<<gn, NB, 0, stream>>>(cnt, partial, rowptr, cursor, n);
    k_padfill<<<gn, NB, 0, stream>>>(rowptr, cnt, adj, n);
    k_scatter<<<ge, NB, 0, stream>>>(src, dst, cursor, adj, e);

    // u0 in d_out; 12 layers ping-pong d_out <-> uws; even count ends in d_out
    float* cur = uout;
    float* nxt = uws;
    for (int l = 0; l < 12; ++l) {
        k_layer<<<gn4, NB, 0, stream>>>(rowptr, cnt, adj, (const float4*)cur, (float4*)nxt, n);
        float* tp = cur; cur = nxt; nxt = tp;
    }
    k_finish<<<gn4, NB, 0, stream>>>((float4*)uout, cnt, n * 4);
}

// Round 4
// 603.977 us; speedup vs baseline: 2.3577x; 2.3577x over previous
//
#include <hip/hip_runtime.h>

// h <- A_norm h, 12 times, in u-space (u = rsqrt(deg).*h):
//   u'[d] = (1/deg[d]) * (u[d] + sum_{s in N(d)} u[s]),  h12 = sqrt(deg).*u12
// CSR built per call with a bucketed, (almost) atomic-free pipeline:
//   hist(dst>>10) -> scan -> reorder (LDS-staged, packed words) ->
//   per-bucket LDS count -> global scan -> per-bucket LDS-cursor place.
// Isolated nodes zeroed at the END (they never propagate, so equivalent).

#define NB 256
#define SBSHIFT 10
#define SBSIZE 1024
#define MAXSB 1024
#define CH 4096
#define RT 256

__global__ void k_zero(int* __restrict__ sbhist, unsigned* __restrict__ mask, int nsb, int nm) {
    int i = blockIdx.x * NB + threadIdx.x;
    if (i < nsb) sbhist[i] = 0;
    if (i < nm) mask[i] = 0u;
}

__global__ void k_hist(const int* __restrict__ dst, int e, int* __restrict__ sbhist, int nsb) {
    __shared__ int lh[MAXSB];
    for (int b = threadIdx.x; b < nsb; b += NB) lh[b] = 0;
    __syncthreads();
    int stride = gridDim.x * NB;
    for (int i = blockIdx.x * NB + threadIdx.x; i < e; i += stride)
        atomicAdd(&lh[dst[i] >> SBSHIFT], 1);
    __syncthreads();
    for (int b = threadIdx.x; b < nsb; b += NB)
        if (lh[b]) atomicAdd(&sbhist[b], lh[b]);
}

__global__ void k_scan_sb(const int* __restrict__ sbhist, int* __restrict__ sbbase,
                          int* __restrict__ bcur, int nsb) {
    __shared__ int sh[MAXSB + 1];
    int t = threadIdx.x;
    if (t < nsb) sh[t] = sbhist[t];
    __syncthreads();
    if (t == 0) {
        int acc = 0;
        for (int b = 0; b < nsb; ++b) { int v = sh[b]; sh[b] = acc; acc += v; }
        sh[nsb] = acc;
    }
    __syncthreads();
    if (t <= nsb) sbbase[t] = sh[t];
    if (t < nsb) bcur[t] = sh[t];
}

// chunk-staged reorder: sedge[pos] = (src<<SBSHIFT)|(dst&(SBSIZE-1)), bucket-sorted
__global__ __launch_bounds__(RT) void k_reorder(const int* __restrict__ src,
                                                const int* __restrict__ dst, int e, int nsb,
                                                int* __restrict__ bcur, int* __restrict__ sedge) {
    __shared__ int lsize[MAXSB];
    __shared__ int lofs[MAXSB];
    __shared__ int ldelta[MAXSB];
    __shared__ int lcur[MAXSB];
    __shared__ int stage[CH];
    __shared__ int gpos[CH];
    int t = threadIdx.x;
    int base = blockIdx.x * CH;
    int cnt_here = e - base; if (cnt_here > CH) cnt_here = CH;
    for (int b = t; b < nsb; b += RT) lsize[b] = 0;
    __syncthreads();
    int myb[16], myw[16];
#pragma unroll
    for (int k = 0; k < 16; ++k) {
        int i = base + k * RT + t;
        if (i < e) {
            int s = src[i], d = dst[i];
            int b = d >> SBSHIFT;
            myb[k] = b;
            myw[k] = (s << SBSHIFT) | (d & (SBSIZE - 1));
            atomicAdd(&lsize[b], 1);
        } else myb[k] = -1;
    }
    __syncthreads();
    if (t == 0) {
        int acc = 0;
        for (int b = 0; b < nsb; ++b) { lofs[b] = acc; acc += lsize[b]; }
    }
    __syncthreads();
    for (int b = t; b < nsb; b += RT) {
        int sz = lsize[b];
        if (sz > 0) {
            int g = atomicAdd(&bcur[b], sz);
            ldelta[b] = g - lofs[b];
        }
        lcur[b] = lofs[b];
    }
    __syncthreads();
#pragma unroll
    for (int k = 0; k < 16; ++k) {
        int b = myb[k];
        if (b >= 0) {
            int sl = atomicAdd(&lcur[b], 1);
            stage[sl] = myw[k];
            gpos[sl] = ldelta[b] + sl;
        }
    }
    __syncthreads();
    for (int s = t; s < cnt_here; s += RT)
        sedge[gpos[s]] = stage[s];
}

__global__ __launch_bounds__(SBSIZE) void k_fine_cnt(const int* __restrict__ sedge,
                                                     const int* __restrict__ sbbase,
                                                     int* __restrict__ cnt, int n) {
    __shared__ int lc[SBSIZE];
    int t = threadIdx.x;
    lc[t] = 0;
    __syncthreads();
    int lo = sbbase[blockIdx.x], hi = sbbase[blockIdx.x + 1];
    for (int i = lo + t; i < hi; i += SBSIZE)
        atomicAdd(&lc[sedge[i] & (SBSIZE - 1)], 1);
    __syncthreads();
    int node = (blockIdx.x << SBSHIFT) + t;
    if (node < n) cnt[node] = lc[t];
}

// ---- exclusive scan of padded counts ((cnt+3)&~3) -> rowptr ----
__global__ void k_scan1(const int* __restrict__ cnt, int* __restrict__ partial, int n) {
    __shared__ int sd[NB];
    int i = blockIdx.x * NB + threadIdx.x;
    sd[threadIdx.x] = (i < n) ? ((cnt[i] + 3) & ~3) : 0;
    __syncthreads();
    for (int s = NB / 2; s > 0; s >>= 1) {
        if (threadIdx.x < s) sd[threadIdx.x] += sd[threadIdx.x + s];
        __syncthreads();
    }
    if (threadIdx.x == 0) partial[blockIdx.x] = sd[0];
}

__global__ void k_scan2(int* __restrict__ partial, int nb) {
    __shared__ int sd[512];
    int t = threadIdx.x;
    int v = (t < nb) ? partial[t] : 0;
    sd[t] = v;
    __syncthreads();
    for (int off = 1; off < 512; off <<= 1) {
        int add = (t >= off) ? sd[t - off] : 0;
        __syncthreads();
        sd[t] += add;
        __syncthreads();
    }
    if (t < nb) partial[t] = sd[t] - v;   // exclusive
}

__global__ void k_scan3(const int* __restrict__ cnt, const int* __restrict__ partial,
                        int* __restrict__ rowptr, int n) {
    __shared__ int sd[NB];
    int i = blockIdx.x * NB + threadIdx.x;
    int v = (i < n) ? ((cnt[i] + 3) & ~3) : 0;
    sd[threadIdx.x] = v;
    __syncthreads();
    for (int off = 1; off < NB; off <<= 1) {
        int add = (threadIdx.x >= off) ? sd[threadIdx.x - off] : 0;
        __syncthreads();
        sd[threadIdx.x] += add;
        __syncthreads();
    }
    int ex = sd[threadIdx.x] - v + partial[blockIdx.x];
    if (i < n) rowptr[i] = ex;
    if (i == n - 1) rowptr[n] = ex + v;
}

__global__ void k_padfill(const int* __restrict__ rowptr, const int* __restrict__ cnt,
                          int* __restrict__ adj, int n) {
    int i = blockIdx.x * NB + threadIdx.x;
    if (i >= n) return;
    int b = rowptr[i] + cnt[i], en = rowptr[i + 1];
    for (int p = b; p < en; ++p) adj[p] = i;
}

__global__ __launch_bounds__(SBSIZE) void k_place(const int* __restrict__ sedge,
                                                  const int* __restrict__ sbbase,
                                                  const int* __restrict__ rowptr,
                                                  const int* __restrict__ cnt,
                                                  unsigned* __restrict__ mask,
                                                  int* __restrict__ adj, int n) {
    __shared__ int lcur[SBSIZE];
    int t = threadIdx.x;
    int node = (blockIdx.x << SBSHIFT) + t;
    lcur[t] = (node < n) ? rowptr[node] : 0;
    __syncthreads();
    int lo = sbbase[blockIdx.x], hi = sbbase[blockIdx.x + 1];
    for (int i = lo + t; i < hi; i += SBSIZE) {
        int w = sedge[i];
        int d = w & (SBSIZE - 1);
        int s = w >> SBSHIFT;
        int pos = atomicAdd(&lcur[d], 1);
        adj[pos] = s;
        if (cnt[s] == 0) atomicOr(&mask[s >> 5], 1u << (s & 31));  // rare
    }
}

// u0 = x * rsqrt(deg) (no masking here; isolated zeroed in k_finish)
__global__ void k_init_u(const float4* __restrict__ x, const int* __restrict__ cnt,
                         float4* __restrict__ u, int n4) {
    int i = blockIdx.x * NB + threadIdx.x;
    if (i >= n4) return;
    int node = i >> 2;
    float is = rsqrtf((float)(cnt[node] + 1));
    float4 v = x[i];
    v.x *= is; v.y *= is; v.z *= is; v.w *= is;
    u[i] = v;
}

// 4 threads per node; lane q owns float4 quadrant q. 8 gathers in flight.
__global__ void k_layer(const int* __restrict__ rowptr, const int* __restrict__ cnt,
                        const int* __restrict__ adj,
                        const float4* __restrict__ u, float4* __restrict__ un, int n) {
    int t = blockIdx.x * NB + threadIdx.x;
    int node = t >> 2, q = t & 3;
    if (node >= n) return;
    int beg = rowptr[node], endp = rowptr[node + 1];
    int deg = cnt[node];
    float corr = (float)(1 - (endp - beg - deg));   // 1 - pads
    float c0 = 1.0f / (float)(deg + 1);
    float4 self = u[(size_t)node * 4 + q];
    float ax = 0.f, ay = 0.f, az = 0.f, aw = 0.f;
    float bx = 0.f, by = 0.f, bz = 0.f, bw = 0.f;
    int p = beg;
    for (; p + 8 <= endp; p += 8) {
        int4 sa = *(const int4*)(adj + p);
        int4 sb = *(const int4*)(adj + p + 4);
        float4 v0 = u[(size_t)sa.x * 4 + q];
        float4 v1 = u[(size_t)sa.y * 4 + q];
        float4 v2 = u[(size_t)sa.z * 4 + q];
        float4 v3 = u[(size_t)sa.w * 4 + q];
        float4 w0 = u[(size_t)sb.x * 4 + q];
        float4 w1 = u[(size_t)sb.y * 4 + q];
        float4 w2 = u[(size_t)sb.z * 4 + q];
        float4 w3 = u[(size_t)sb.w * 4 + q];
        ax += (v0.x + v1.x) + (v2.x + v3.x);
        ay += (v0.y + v1.y) + (v2.y + v3.y);
        az += (v0.z + v1.z) + (v2.z + v3.z);
        aw += (v0.w + v1.w) + (v2.w + v3.w);
        bx += (w0.x + w1.x) + (w2.x + w3.x);
        by += (w0.y + w1.y) + (w2.y + w3.y);
        bz += (w0.z + w1.z) + (w2.z + w3.z);
        bw += (w0.w + w1.w) + (w2.w + w3.w);
    }
    if (p < endp) {
        int4 sa = *(const int4*)(adj + p);
        float4 v0 = u[(size_t)sa.x * 4 + q];
        float4 v1 = u[(size_t)sa.y * 4 + q];
        float4 v2 = u[(size_t)sa.z * 4 + q];
        float4 v3 = u[(size_t)sa.w * 4 + q];
        ax += (v0.x + v1.x) + (v2.x + v3.x);
        ay += (v0.y + v1.y) + (v2.y + v3.y);
        az += (v0.z + v1.z) + (v2.z + v3.z);
        aw += (v0.w + v1.w) + (v2.w + v3.w);
    }
    float4 r;
    r.x = (ax + bx + corr * self.x) * c0;
    r.y = (ay + by + corr * self.y) * c0;
    r.z = (az + bz + corr * self.z) * c0;
    r.w = (aw + bw + corr * self.w) * c0;
    un[(size_t)node * 4 + q] = r;
}

// h12 = sqrt(deg).*u12, zero if isolated (cnt==0 and never seen as src)
__global__ void k_finish(float4* __restrict__ h, const int* __restrict__ cnt,
                         const unsigned* __restrict__ mask, int n4) {
    int i = blockIdx.x * NB + threadIdx.x;
    if (i >= n4) return;
    int node = i >> 2;
    int c = cnt[node];
    bool nonisol = (c > 0) || (((mask[node >> 5] >> (node & 31)) & 1u) != 0u);
    float s = nonisol ? sqrtf((float)(c + 1)) : 0.0f;
    float4 v = h[i];
    v.x *= s; v.y *= s; v.z *= s; v.w *= s;
    h[i] = v;
}

extern "C" void kernel_launch(void* const* d_in, const int* in_sizes, int n_in,
                              void* d_out, int out_size, void* d_ws, size_t ws_size,
                              hipStream_t stream) {
    const float* x  = (const float*)d_in[0];
    const int*   ei = (const int*)d_in[1];
    const int n = in_sizes[0] / 16;   // 100000
    const int e = in_sizes[1] / 2;    // 3200000
    const int* src = ei;
    const int* dst = ei + e;
    const int nm  = (n + 31) / 32;
    const int nsb = (n + SBSIZE - 1) >> SBSHIFT;   // 98

    char* ws = (char*)d_ws;
    auto take = [&](size_t bytes) {
        char* p = ws;
        ws += (bytes + 255) & ~(size_t)255;
        return p;
    };
    int*      sbhist  = (int*)take((size_t)MAXSB * sizeof(int));
    int*      sbbase  = (int*)take((size_t)(MAXSB + 1) * sizeof(int));
    int*      bcur    = (int*)take((size_t)MAXSB * sizeof(int));
    unsigned* mask    = (unsigned*)take((size_t)nm * sizeof(unsigned));
    int*      cnt     = (int*)take((size_t)n * sizeof(int));
    int*      rowptr  = (int*)take((size_t)(n + 1) * sizeof(int));
    int*      partial = (int*)take(512 * sizeof(int));
    int*      sedge   = (int*)take((size_t)e * sizeof(int));
    int*      adj     = (int*)take((size_t)(e + 4 * n) * sizeof(int));
    float*    uws     = (float*)take((size_t)n * 16 * sizeof(float));
    float*    uout    = (float*)d_out;

    const int gn  = (n + NB - 1) / NB;       // 391
    const int gn4 = (n * 4 + NB - 1) / NB;   // 1563
    const int gre = (e + CH - 1) / CH;       // 782
    const int gz  = (((nsb > nm) ? nsb : nm) + NB - 1) / NB;

    k_zero<<<gz, NB, 0, stream>>>(sbhist, mask, nsb, nm);
    k_hist<<<256, NB, 0, stream>>>(dst, e, sbhist, nsb);
    k_scan_sb<<<1, MAXSB, 0, stream>>>(sbhist, sbbase, bcur, nsb);
    k_reorder<<<gre, RT, 0, stream>>>(src, dst, e, nsb, bcur, sedge);
    k_fine_cnt<<<nsb, SBSIZE, 0, stream>>>(sedge, sbbase, cnt, n);
    k_scan1<<<gn, NB, 0, stream>>>(cnt, partial, n);
    k_scan2<<<1, 512, 0, stream>>>(partial, gn);
    k_scan3<<<gn, NB, 0, stream>>>(cnt, partial, rowptr, n);
    k_padfill<<<gn, NB, 0, stream>>>(rowptr, cnt, adj, n);
    k_place<<<nsb, SBSIZE, 0, stream>>>(sedge, sbbase, rowptr, cnt, mask, adj, n);
    k_init_u<<<gn4, NB, 0, stream>>>((const float4*)x, cnt, (float4*)uout, n * 4);

    float* cur = uout;   // 12 layers (even) -> result ends in d_out
    float* nxt = uws;
    for (int l = 0; l < 12; ++l) {
        k_layer<<<gn4, NB, 0, stream>>>(rowptr, cnt, adj, (const float4*)cur, (float4*)nxt, n);
        float* tp = cur; cur = nxt; nxt = tp;
    }
    k_finish<<<gn4, NB, 0, stream>>>((float4*)uout, cnt, mask, n * 4);
}

// Round 5
// 566.208 us; speedup vs baseline: 2.5150x; 1.0667x over previous
//
#include <hip/hip_runtime.h>

// h <- A_norm h, 12 times, in u-space (u = rsqrt(deg).*h):
//   u'[d] = (1/deg[d]) * (u[d] + sum_{s in N(d)} u[s]),  h12 = sqrt(deg).*u12
// CSR built per call, atomic-light bucketed pipeline (256-node buckets):
//   hist(dst>>8) -> scan -> reorder (LDS-staged, packed (src<<8|dstlocal)) ->
//   per-bucket LDS count -> scan -> per-bucket LDS-cursor place (+pad fill).
// Isolated nodes zeroed at the END (they never propagate -> equivalent).

#define NB 256
#define SBSHIFT 8
#define SBSIZE 256
#define NSBP 512          // padded bin count (nsb = ceil(n/256) = 391 <= 512)
#define CH 4096           // edges per reorder chunk
#define RT 512            // reorder threads
#define EPT 8             // CH / RT

__global__ void k_zero(int* __restrict__ sbhist, unsigned* __restrict__ mask, int nsb, int nm) {
    int i = blockIdx.x * NB + threadIdx.x;
    if (i < nsb) sbhist[i] = 0;
    if (i < nm) mask[i] = 0u;
}

__global__ void k_hist(const int* __restrict__ dst, int e, int* __restrict__ sbhist, int nsb) {
    __shared__ int lh[NSBP];
    for (int b = threadIdx.x; b < NSBP; b += NB) lh[b] = 0;
    __syncthreads();
    int stride = gridDim.x * NB;
    for (int i = blockIdx.x * NB + threadIdx.x; i < e; i += stride)
        atomicAdd(&lh[dst[i] >> SBSHIFT], 1);
    __syncthreads();
    for (int b = threadIdx.x; b < nsb; b += NB)
        if (lh[b]) atomicAdd(&sbhist[b], lh[b]);
}

__global__ __launch_bounds__(NSBP) void k_scan_sb(const int* __restrict__ sbhist,
                                                  int* __restrict__ sbbase,
                                                  int* __restrict__ bcur, int nsb) {
    __shared__ int sh[NSBP];
    int t = threadIdx.x;
    int v = (t < nsb) ? sbhist[t] : 0;
    sh[t] = v;
    __syncthreads();
    for (int off = 1; off < NSBP; off <<= 1) {
        int add = (t >= off) ? sh[t - off] : 0;
        __syncthreads();
        sh[t] += add;
        __syncthreads();
    }
    int incl = sh[t];
    if (t < nsb) { sbbase[t] = incl - v; bcur[t] = incl - v; }
    if (t == nsb - 1) sbbase[nsb] = incl;
}

// chunk-staged reorder: sedge[pos] = (src<<8)|(dst&255), bucket-sorted
__global__ __launch_bounds__(RT) void k_reorder(const int* __restrict__ src,
                                                const int* __restrict__ dst, int e,
                                                int* __restrict__ bcur, int* __restrict__ sedge) {
    __shared__ int lsize[NSBP];
    __shared__ int lscan[NSBP];
    __shared__ int ldelta[NSBP];
    __shared__ int lcur[NSBP];
    __shared__ int stage[CH];
    __shared__ int gpos[CH];
    int t = threadIdx.x;
    int base = blockIdx.x * CH;
    int cnt_here = e - base; if (cnt_here > CH) cnt_here = CH;
    lsize[t] = 0;
    __syncthreads();
    int myb[EPT], myw[EPT];
#pragma unroll
    for (int k = 0; k < EPT; ++k) {
        int i = base + k * RT + t;
        if (i < e) {
            int s = src[i], d = dst[i];
            int b = d >> SBSHIFT;
            myb[k] = b;
            myw[k] = (s << SBSHIFT) | (d & (SBSIZE - 1));
            atomicAdd(&lsize[b], 1);
        } else myb[k] = -1;
    }
    __syncthreads();
    int v = lsize[t];
    lscan[t] = v;
    __syncthreads();
    for (int off = 1; off < NSBP; off <<= 1) {
        int add = (t >= off) ? lscan[t - off] : 0;
        __syncthreads();
        lscan[t] += add;
        __syncthreads();
    }
    int excl = lscan[t] - v;
    if (v > 0) ldelta[t] = atomicAdd(&bcur[t], v) - excl;
    lcur[t] = excl;
    __syncthreads();
#pragma unroll
    for (int k = 0; k < EPT; ++k) {
        int b = myb[k];
        if (b >= 0) {
            int sl = atomicAdd(&lcur[b], 1);
            stage[sl] = myw[k];
            gpos[sl] = ldelta[b] + sl;
        }
    }
    __syncthreads();
    for (int s2 = t; s2 < cnt_here; s2 += RT)
        sedge[gpos[s2]] = stage[s2];
}

__global__ __launch_bounds__(SBSIZE) void k_fine_cnt(const int* __restrict__ sedge,
                                                     const int* __restrict__ sbbase,
                                                     int* __restrict__ cnt, int n) {
    __shared__ int lc[SBSIZE];
    int t = threadIdx.x;
    lc[t] = 0;
    __syncthreads();
    int lo = sbbase[blockIdx.x], hi = sbbase[blockIdx.x + 1];
    for (int i = lo + t; i < hi; i += SBSIZE)
        atomicAdd(&lc[sedge[i] & (SBSIZE - 1)], 1);
    __syncthreads();
    int node = (blockIdx.x << SBSHIFT) + t;
    if (node < n) cnt[node] = lc[t];
}

// ---- exclusive scan of padded counts ((cnt+3)&~3) -> rowptr ----
__global__ void k_scan1(const int* __restrict__ cnt, int* __restrict__ partial, int n) {
    __shared__ int sd[NB];
    int i = blockIdx.x * NB + threadIdx.x;
    sd[threadIdx.x] = (i < n) ? ((cnt[i] + 3) & ~3) : 0;
    __syncthreads();
    for (int s = NB / 2; s > 0; s >>= 1) {
        if (threadIdx.x < s) sd[threadIdx.x] += sd[threadIdx.x + s];
        __syncthreads();
    }
    if (threadIdx.x == 0) partial[blockIdx.x] = sd[0];
}

__global__ void k_scan2(int* __restrict__ partial, int nb) {
    __shared__ int sd[512];
    int t = threadIdx.x;
    int v = (t < nb) ? partial[t] : 0;
    sd[t] = v;
    __syncthreads();
    for (int off = 1; off < 512; off <<= 1) {
        int add = (t >= off) ? sd[t - off] : 0;
        __syncthreads();
        sd[t] += add;
        __syncthreads();
    }
    if (t < nb) partial[t] = sd[t] - v;   // exclusive
}

__global__ void k_scan3(const int* __restrict__ cnt, const int* __restrict__ partial,
                        int* __restrict__ rowptr, int n) {
    __shared__ int sd[NB];
    int i = blockIdx.x * NB + threadIdx.x;
    int v = (i < n) ? ((cnt[i] + 3) & ~3) : 0;
    sd[threadIdx.x] = v;
    __syncthreads();
    for (int off = 1; off < NB; off <<= 1) {
        int add = (threadIdx.x >= off) ? sd[threadIdx.x - off] : 0;
        __syncthreads();
        sd[threadIdx.x] += add;
        __syncthreads();
    }
    int ex = sd[threadIdx.x] - v + partial[blockIdx.x];
    if (i < n) rowptr[i] = ex;
    if (i == n - 1) rowptr[n] = ex + v;
}

// per-bucket place via LDS cursors; pad slots filled in epilogue
__global__ __launch_bounds__(SBSIZE) void k_place(const int* __restrict__ sedge,
                                                  const int* __restrict__ sbbase,
                                                  const int* __restrict__ rowptr,
                                                  const int* __restrict__ cnt,
                                                  unsigned* __restrict__ mask,
                                                  int* __restrict__ adj, int n) {
    __shared__ int lcur[SBSIZE];
    int t = threadIdx.x;
    int node = (blockIdx.x << SBSHIFT) + t;
    lcur[t] = (node < n) ? rowptr[node] : 0;
    __syncthreads();
    int lo = sbbase[blockIdx.x], hi = sbbase[blockIdx.x + 1];
    for (int i = lo + t; i < hi; i += SBSIZE) {
        int w = sedge[i];
        int d = w & (SBSIZE - 1);
        int s = w >> SBSHIFT;
        int pos = atomicAdd(&lcur[d], 1);
        adj[pos] = s;
        if (cnt[s] == 0) atomicOr(&mask[s >> 5], 1u << (s & 31));  // rare
    }
    __syncthreads();
    if (node < n) {
        int en = rowptr[node + 1];
        for (int p = lcur[t]; p < en; ++p) adj[p] = node;  // lcur[t]==rowptr+cnt
    }
}

// u0 = x * rsqrt(deg) (no masking here; isolated zeroed in k_finish)
__global__ void k_init_u(const float4* __restrict__ x, const int* __restrict__ cnt,
                         float4* __restrict__ u, int n4) {
    int i = blockIdx.x * NB + threadIdx.x;
    if (i >= n4) return;
    int node = i >> 2;
    float is = rsqrtf((float)(cnt[node] + 1));
    float4 v = x[i];
    v.x *= is; v.y *= is; v.z *= is; v.w *= is;
    u[i] = v;
}

// 4 threads per node; lane q owns float4 quadrant q. 8 gathers in flight.
__global__ void k_layer(const int* __restrict__ rowptr, const int* __restrict__ cnt,
                        const int* __restrict__ adj,
                        const float4* __restrict__ u, float4* __restrict__ un, int n) {
    int t = blockIdx.x * NB + threadIdx.x;
    int node = t >> 2, q = t & 3;
    if (node >= n) return;
    int beg = rowptr[node], endp = rowptr[node + 1];
    int deg = cnt[node];
    float corr = (float)(1 - (endp - beg - deg));   // 1 - pads
    float c0 = 1.0f / (float)(deg + 1);
    float4 self = u[(size_t)node * 4 + q];
    float ax = 0.f, ay = 0.f, az = 0.f, aw = 0.f;
    float bx = 0.f, by = 0.f, bz = 0.f, bw = 0.f;
    int p = beg;
    for (; p + 8 <= endp; p += 8) {
        int4 sa = *(const int4*)(adj + p);
        int4 sb = *(const int4*)(adj + p + 4);
        float4 v0 = u[(size_t)sa.x * 4 + q];
        float4 v1 = u[(size_t)sa.y * 4 + q];
        float4 v2 = u[(size_t)sa.z * 4 + q];
        float4 v3 = u[(size_t)sa.w * 4 + q];
        float4 w0 = u[(size_t)sb.x * 4 + q];
        float4 w1 = u[(size_t)sb.y * 4 + q];
        float4 w2 = u[(size_t)sb.z * 4 + q];
        float4 w3 = u[(size_t)sb.w * 4 + q];
        ax += (v0.x + v1.x) + (v2.x + v3.x);
        ay += (v0.y + v1.y) + (v2.y + v3.y);
        az += (v0.z + v1.z) + (v2.z + v3.z);
        aw += (v0.w + v1.w) + (v2.w + v3.w);
        bx += (w0.x + w1.x) + (w2.x + w3.x);
        by += (w0.y + w1.y) + (w2.y + w3.y);
        bz += (w0.z + w1.z) + (w2.z + w3.z);
        bw += (w0.w + w1.w) + (w2.w + w3.w);
    }
    if (p < endp) {
        int4 sa = *(const int4*)(adj + p);
        float4 v0 = u[(size_t)sa.x * 4 + q];
        float4 v1 = u[(size_t)sa.y * 4 + q];
        float4 v2 = u[(size_t)sa.z * 4 + q];
        float4 v3 = u[(size_t)sa.w * 4 + q];
        ax += (v0.x + v1.x) + (v2.x + v3.x);
        ay += (v0.y + v1.y) + (v2.y + v3.y);
        az += (v0.z + v1.z) + (v2.z + v3.z);
        aw += (v0.w + v1.w) + (v2.w + v3.w);
    }
    float4 r;
    r.x = (ax + bx + corr * self.x) * c0;
    r.y = (ay + by + corr * self.y) * c0;
    r.z = (az + bz + corr * self.z) * c0;
    r.w = (aw + bw + corr * self.w) * c0;
    un[(size_t)node * 4 + q] = r;
}

// h12 = sqrt(deg).*u12, zero if isolated (cnt==0 and never seen as src)
__global__ void k_finish(float4* __restrict__ h, const int* __restrict__ cnt,
                         const unsigned* __restrict__ mask, int n4) {
    int i = blockIdx.x * NB + threadIdx.x;
    if (i >= n4) return;
    int node = i >> 2;
    int c = cnt[node];
    bool nonisol = (c > 0) || (((mask[node >> 5] >> (node & 31)) & 1u) != 0u);
    float s = nonisol ? sqrtf((float)(c + 1)) : 0.0f;
    float4 v = h[i];
    v.x *= s; v.y *= s; v.z *= s; v.w *= s;
    h[i] = v;
}

extern "C" void kernel_launch(void* const* d_in, const int* in_sizes, int n_in,
                              void* d_out, int out_size, void* d_ws, size_t ws_size,
                              hipStream_t stream) {
    const float* x  = (const float*)d_in[0];
    const int*   ei = (const int*)d_in[1];
    const int n = in_sizes[0] / 16;   // 100000
    const int e = in_sizes[1] / 2;    // 3200000
    const int* src = ei;
    const int* dst = ei + e;
    const int nm  = (n + 31) / 32;
    const int nsb = (n + SBSIZE - 1) >> SBSHIFT;   // 391

    char* ws = (char*)d_ws;
    auto take = [&](size_t bytes) {
        char* p = ws;
        ws += (bytes + 255) & ~(size_t)255;
        return p;
    };
    int*      sbhist  = (int*)take((size_t)NSBP * sizeof(int));
    int*      sbbase  = (int*)take((size_t)(NSBP + 1) * sizeof(int));
    int*      bcur    = (int*)take((size_t)NSBP * sizeof(int));
    unsigned* mask    = (unsigned*)take((size_t)nm * sizeof(unsigned));
    int*      cnt     = (int*)take((size_t)n * sizeof(int));
    int*      rowptr  = (int*)take((size_t)(n + 1) * sizeof(int));
    int*      partial = (int*)take(512 * sizeof(int));
    int*      sedge   = (int*)take((size_t)e * sizeof(int));
    int*      adj     = (int*)take((size_t)(e + 4 * n) * sizeof(int));
    float*    uws     = (float*)take((size_t)n * 16 * sizeof(float));
    float*    uout    = (float*)d_out;

    const int gn  = (n + NB - 1) / NB;       // 391
    const int gn4 = (n * 4 + NB - 1) / NB;   // 1563
    const int gre = (e + CH - 1) / CH;       // 782
    const int gz  = (((nsb > nm) ? nsb : nm) + NB - 1) / NB;

    k_zero<<<gz, NB, 0, stream>>>(sbhist, mask, nsb, nm);
    k_hist<<<512, NB, 0, stream>>>(dst, e, sbhist, nsb);
    k_scan_sb<<<1, NSBP, 0, stream>>>(sbhist, sbbase, bcur, nsb);
    k_reorder<<<gre, RT, 0, stream>>>(src, dst, e, bcur, sedge);
    k_fine_cnt<<<nsb, SBSIZE, 0, stream>>>(sedge, sbbase, cnt, n);
    k_scan1<<<gn, NB, 0, stream>>>(cnt, partial, n);
    k_scan2<<<1, 512, 0, stream>>>(partial, gn);
    k_scan3<<<gn, NB, 0, stream>>>(cnt, partial, rowptr, n);
    k_place<<<nsb, SBSIZE, 0, stream>>>(sedge, sbbase, rowptr, cnt, mask, adj, n);
    k_init_u<<<gn4, NB, 0, stream>>>((const float4*)x, cnt, (float4*)uout, n * 4);

    float* cur = uout;   // 12 layers (even) -> result ends in d_out
    float* nxt = uws;
    for (int l = 0; l < 12; ++l) {
        k_layer<<<gn4, NB, 0, stream>>>(rowptr, cnt, adj, (const float4*)cur, (float4*)nxt, n);
        float* tp = cur; cur = nxt; nxt = tp;
    }
    k_finish<<<gn4, NB, 0, stream>>>((float4*)uout, cnt, mask, n * 4);
}